// Round 1
// baseline (23348.392 us; speedup 1.0000x reference)
//
#include <hip/hip_runtime.h>
#include <math.h>

#define Bz 32
#define Lz 2048
#define Iz 64
#define Hz 512
#define HALFz 256
#define DTz 0.05f

#define FMA4(P, S, W) do { (P).x = fmaf((S), (W).x, (P).x); (P).y = fmaf((S), (W).y, (P).y); \
                           (P).z = fmaf((S), (W).z, (P).z); (P).w = fmaf((S), (W).w, (P).w); } while(0)

// xin[b][t][h] = sum_i x[b][t][i]*x2h[i][h] + bias[h]
// One block handles 32 (b,t) rows; thread u owns output column h=u with x2h column cached in regs.
__global__ __launch_bounds__(512) void prep_xin_kernel(
    const float* __restrict__ x, const float* __restrict__ x2h,
    const float* __restrict__ bias, float* __restrict__ xin) {
  __shared__ float xs[32][Iz];
  const long base = (long)blockIdx.x * 32;   // flattened row index r = b*L + t
  const int u = threadIdx.x;
  for (int i = u; i < 32 * Iz; i += 512)
    xs[i >> 6][i & 63] = x[base * Iz + i];
  __syncthreads();
  float w[Iz];
  #pragma unroll
  for (int k = 0; k < Iz; ++k) w[k] = x2h[k * Hz + u];
  const float bu = bias[u];
  for (int r = 0; r < 32; ++r) {
    float acc = bu;
    #pragma unroll
    for (int k = 0; k < Iz; ++k) acc = fmaf(xs[r][k], w[k], acc);
    xin[(base + r) * Hz + u] = acc;
  }
}

// Persistent scan: one block per batch element, 512 threads, thread u owns h=u state.
template<bool XIN>
__global__ __launch_bounds__(512) void coesn_scan_kernel(
    const float* __restrict__ x, const float* __restrict__ x2h,
    const float* __restrict__ h2h, const float* __restrict__ bias,
    const float* __restrict__ gam, const float* __restrict__ eps,
    const float* __restrict__ W_rff, const float* __restrict__ xin,
    float* __restrict__ out) {
  const int b = blockIdx.x;
  const int u = threadIdx.x;
  __shared__ __align__(16) float hy_lds[Hz];
  __shared__ __align__(16) float x_lds[Iz];
  __shared__ float4 part[4][128];   // [kq][g] partial float4 (cols 4g..4g+3)
  __shared__ float wx_lds[HALFz];

  float hy = 0.f, hz = 0.f, zsum = 0.f;
  const float bu = XIN ? 0.f : bias[u];
  const float gu = gam[u];
  const float eu = eps[u];

  const int kq = u >> 7;      // 0..3  : K-slice for h2h/x2h
  const int g  = u & 127;     // column group: cols 4g..4g+3
  const int jj = u >> 2;      // 0..127: RFF rows jj and jj+128
  const int ks = u & 3;       // RFF K-split lane

  const float4* __restrict__ H4 = (const float4*)h2h;
  const float4* __restrict__ X2 = (const float4*)x2h;
  const float4* __restrict__ W4 = (const float4*)W_rff;
  const float4* __restrict__ XG = (const float4*)x;
  const float4* hy4 = (const float4*)hy_lds;

  hy_lds[u] = 0.f;
  if (!XIN && u < 16) ((float4*)x_lds)[u] = XG[(long)b * Lz * 16 + u];
  __syncthreads();

  for (int t = 0; t < Lz; ++t) {
    float xinv = 0.f;
    if (XIN) xinv = xin[((long)b * Lz + t) * Hz + u];   // issued early, coalesced

    // ---- phase 1: partial matvec (reads hy_lds of step t-1, x_lds) ----
    float4 p = make_float4(0.f, 0.f, 0.f, 0.f);
    {
      const float4* hp = (const float4*)&hy_lds[kq << 7];
      #pragma unroll 8
      for (int k4 = 0; k4 < 32; ++k4) {
        float4 hv = hp[k4];                               // wave-uniform broadcast
        const float4* wr = &H4[(size_t)((kq << 7) + (k4 << 2)) * 128 + g];
        float4 w0 = wr[0];
        float4 w1 = wr[128];
        float4 w2 = wr[256];
        float4 w3 = wr[384];
        FMA4(p, hv.x, w0);
        FMA4(p, hv.y, w1);
        FMA4(p, hv.z, w2);
        FMA4(p, hv.w, w3);
      }
      if (!XIN) {
        const float4* xp = (const float4*)&x_lds[kq << 4];
        #pragma unroll
        for (int k4 = 0; k4 < 4; ++k4) {
          float4 xv = xp[k4];
          const float4* wr = &X2[(size_t)((kq << 4) + (k4 << 2)) * 128 + g];
          float4 w0 = wr[0];
          float4 w1 = wr[128];
          float4 w2 = wr[256];
          float4 w3 = wr[384];
          FMA4(p, xv.x, w0);
          FMA4(p, xv.y, w1);
          FMA4(p, xv.z, w2);
          FMA4(p, xv.w, w3);
        }
      }
    }
    part[kq][g] = p;
    __syncthreads();   // A

    // ---- phase 2: reduce partials, state update, publish new hy ----
    {
      const float* pp = (const float*)part;
      float s = (pp[u] + pp[512 + u]) + (pp[1024 + u] + pp[1536 + u]);
      float pre = tanhf(s + bu + xinv);
      float hzn = fmaf(DTz, pre - gu * hy - eu * hz, hz);
      hy = fmaf(DTz, hzn, hy);
      hz = hzn;
      hy_lds[u] = hy;
      if (!XIN && u < 16 && t + 1 < Lz)
        ((float4*)x_lds)[u] = XG[((long)b * Lz + (t + 1)) * 16 + u];
    }
    __syncthreads();   // B

    // ---- phase 3: RFF matvec wx = hy @ W_rff^T, 4-lane K-split ----
    {
      float4 acc0 = make_float4(0.f,0.f,0.f,0.f), acc1 = make_float4(0.f,0.f,0.f,0.f);
      #pragma unroll 4
      for (int it = 0; it < 32; ++it) {
        int k4 = (it << 2) + ks;                    // float4-chunk index in [0,128)
        float4 hv = hy4[k4];
        float4 w0 = W4[(size_t)jj * 128 + k4];
        float4 w1 = W4[(size_t)(jj + 128) * 128 + k4];
        acc0.x = fmaf(hv.x, w0.x, acc0.x);
        acc0.y = fmaf(hv.y, w0.y, acc0.y);
        acc0.z = fmaf(hv.z, w0.z, acc0.z);
        acc0.w = fmaf(hv.w, w0.w, acc0.w);
        acc1.x = fmaf(hv.x, w1.x, acc1.x);
        acc1.y = fmaf(hv.y, w1.y, acc1.y);
        acc1.z = fmaf(hv.z, w1.z, acc1.z);
        acc1.w = fmaf(hv.w, w1.w, acc1.w);
      }
      float a0 = (acc0.x + acc0.y) + (acc0.z + acc0.w);
      float a1 = (acc1.x + acc1.y) + (acc1.z + acc1.w);
      a0 += __shfl_xor(a0, 1); a0 += __shfl_xor(a0, 2);
      a1 += __shfl_xor(a1, 1); a1 += __shfl_xor(a1, 2);
      if (ks == 0) { wx_lds[jj] = a0; wx_lds[jj + 128] = a1; }
    }
    __syncthreads();   // C

    // ---- phase 4: cos/sin accumulate (wave-uniform branch) ----
    {
      float v = wx_lds[u & 255];
      zsum += (u < HALFz) ? cosf(v) : sinf(v);
    }
  }

  // outputs: mu = zsum * inv_sqrt_half / L, then final hy
  out[(long)b * Hz + u] = zsum * (0.0625f / 2048.f);
  out[(long)Bz * Hz + (long)b * Hz + u] = hy;
}

extern "C" void kernel_launch(void* const* d_in, const int* in_sizes, int n_in,
                              void* d_out, int out_size, void* d_ws, size_t ws_size,
                              hipStream_t stream) {
  const float* x    = (const float*)d_in[0];
  const float* x2h  = (const float*)d_in[1];
  const float* h2h  = (const float*)d_in[2];
  const float* bias = (const float*)d_in[3];
  const float* gam  = (const float*)d_in[4];
  const float* eps  = (const float*)d_in[5];
  const float* wrff = (const float*)d_in[6];
  float* out = (float*)d_out;

  const size_t xin_bytes = (size_t)Bz * Lz * Hz * sizeof(float);
  if (ws_size >= xin_bytes) {
    float* xin = (float*)d_ws;
    prep_xin_kernel<<<(Bz * Lz) / 32, 512, 0, stream>>>(x, x2h, bias, xin);
    coesn_scan_kernel<true><<<Bz, 512, 0, stream>>>(x, x2h, h2h, bias, gam, eps, wrff, xin, out);
  } else {
    coesn_scan_kernel<false><<<Bz, 512, 0, stream>>>(x, x2h, h2h, bias, gam, eps, wrff, nullptr, out);
  }
}

// Round 2
// 9891.283 us; speedup vs baseline: 2.3605x; 2.3605x over previous
//
#include <hip/hip_runtime.h>
#include <math.h>

#define Bz 32
#define Lz 2048
#define Iz 64
#define Hz 512
#define HALFz 256
#define DTz 0.05f
#define NMEM 8
#define TPB 512

#define FMA4(P, S, W) do { (P).x = fmaf((S), (W).x, (P).x); (P).y = fmaf((S), (W).y, (P).y); \
                           (P).z = fmaf((S), (W).z, (P).z); (P).w = fmaf((S), (W).w, (P).w); } while(0)

// ---------------- cooperative 8-blocks-per-batch kernel ----------------
// block = (b = blockIdx&31, m = blockIdx>>5). Member m owns H-columns [m*64, m*64+64)
// and RFF rows [m*32, m*32+32). h2h/x2h column slice lives in LDS (rows 0..575),
// W_rff rows live in registers. Per step: one cross-member hy exchange via
// agent-scope atomics in d_ws (double-buffered) + release/acquire counter.
__global__ __launch_bounds__(TPB, 1) void coesn_coop(
    const float* __restrict__ x, const float* __restrict__ x2h,
    const float* __restrict__ h2h, const float* __restrict__ bias,
    const float* __restrict__ gam, const float* __restrict__ eps,
    const float* __restrict__ W_rff, float* __restrict__ gbuf,
    unsigned* __restrict__ cnt, float* __restrict__ out) {
  extern __shared__ float smem[];
  float* hs   = smem;                  // [576][64] weight slice (h2h rows 0..511, x2h rows 512..575)
  float* hyf  = smem + 576 * 64;       // 512 floats, XOR-swizzled float4 chunks
  float* xb   = hyf + 512;             // [2][64] x_t double buffer
  float* part = xb + 128;              // [8 waves][16 cg] float4 partials

  const int b  = blockIdx.x & 31;
  const int m  = blockIdx.x >> 5;
  const int u  = threadIdx.x;
  const int c0 = m * 64;

  // ---- stage weights into LDS (one-time) ----
  for (int idx = u; idx < Hz * 64; idx += TPB)
    hs[idx] = h2h[(size_t)(idx >> 6) * Hz + c0 + (idx & 63)];
  for (int idx = u; idx < Iz * 64; idx += TPB)
    hs[(Hz + (idx >> 6)) * 64 + (idx & 63)] = x2h[(size_t)(idx >> 6) * Hz + c0 + (idx & 63)];

  // ---- W_rff rows into registers ----
  const int rloc = u >> 4;   // 0..31 local RFF row
  const int kseg = u & 15;   // 16 K-segments of 32
  float wr[32];
  {
    const float* wp = W_rff + (size_t)(m * 32 + rloc) * Hz + kseg * 32;
    #pragma unroll
    for (int j = 0; j < 32; ++j) wr[j] = wp[j];
  }

  float hy = 0.f, hz = 0.f, bu = 0.f, gu = 0.f, eu = 0.f;
  if (u < 64) { bu = bias[c0 + u]; gu = gam[c0 + u]; eu = eps[c0 + u]; }
  hyf[u] = 0.f;
  if (u < 16) ((float4*)xb)[u] = ((const float4*)(x + (size_t)b * Lz * Iz))[u];

  float zc = 0.f, zs = 0.f;
  unsigned* cb = cnt + b * 32;   // 128B-padded per-group counter
  __syncthreads();

  const int cg  = u & 15;    // 4 output columns 4cg..4cg+3
  const int ksl = u >> 4;    // 0..31 K-slice (16 hy rows + 2 x rows each)

  for (int t = 0; t < Lz; ++t) {
    // ---- phase A: matvec partials (hy(t) @ h2h_slice + x(t) @ x2h_slice) ----
    float hv[16];
    #pragma unroll
    for (int j = 0; j < 4; ++j) {
      int q = ksl * 4 + j;
      float4 h4 = ((const float4*)hyf)[q ^ ((q >> 3) & 7)];
      hv[4 * j] = h4.x; hv[4 * j + 1] = h4.y; hv[4 * j + 2] = h4.z; hv[4 * j + 3] = h4.w;
    }
    float4 p = make_float4(0.f, 0.f, 0.f, 0.f);
    #pragma unroll
    for (int k = 0; k < 16; ++k) {
      float4 w4 = ((const float4*)(hs + (ksl * 16 + k) * 64))[cg];
      FMA4(p, hv[k], w4);
    }
    const float* xcur = xb + (t & 1) * 64;
    #pragma unroll
    for (int j = 0; j < 2; ++j) {
      float xv = xcur[ksl * 2 + j];
      float4 w4 = ((const float4*)(hs + (Hz + ksl * 2 + j) * 64))[cg];
      FMA4(p, xv, w4);
    }
    if (u < 16 && t + 1 < Lz)
      ((float4*)(xb + ((t + 1) & 1) * 64))[u] =
          ((const float4*)(x + ((size_t)b * Lz + (t + 1)) * Iz))[u];
    // reduce 4 K-slices within each wave (lanes l, l^16, l^32, l^48 share cg)
    p.x += __shfl_xor(p.x, 16); p.y += __shfl_xor(p.y, 16);
    p.z += __shfl_xor(p.z, 16); p.w += __shfl_xor(p.w, 16);
    p.x += __shfl_xor(p.x, 32); p.y += __shfl_xor(p.y, 32);
    p.z += __shfl_xor(p.z, 32); p.w += __shfl_xor(p.w, 32);
    const int lane = u & 63, wv = u >> 6;
    if (lane < 16) ((float4*)part)[wv * 16 + lane] = p;
    __syncthreads();

    // ---- phase B: final reduce + state update on owner threads (cols c0+u) ----
    if (u < 64) {
      float s = 0.f;
      #pragma unroll
      for (int j = 0; j < 8; ++j) s += part[j * 64 + u];
      float pre = tanhf(s + bu);
      float hzn = fmaf(DTz, pre - gu * hy - eu * hz, hz);
      hy = fmaf(DTz, hzn, hy);
      hz = hzn;
      __hip_atomic_store(gbuf + ((t + 1) & 1) * (Bz * Hz) + b * Hz + c0 + u, hy,
                         __ATOMIC_RELAXED, __HIP_MEMORY_SCOPE_AGENT);
    }
    if (u == 0) {
      __hip_atomic_fetch_add(cb, 1u, __ATOMIC_RELEASE, __HIP_MEMORY_SCOPE_AGENT);
      const unsigned target = (unsigned)(NMEM * (t + 1));
      unsigned v; long guard = 0;
      do { v = __hip_atomic_load(cb, __ATOMIC_RELAXED, __HIP_MEMORY_SCOPE_AGENT); }
      while (v < target && ++guard < (1L << 22));
      (void)__hip_atomic_load(cb, __ATOMIC_ACQUIRE, __HIP_MEMORY_SCOPE_AGENT);
    }
    __syncthreads();

    // ---- phase D: read back full hy(t+1), store swizzled into LDS ----
    {
      float v = __hip_atomic_load(gbuf + ((t + 1) & 1) * (Bz * Hz) + b * Hz + u,
                                  __ATOMIC_RELAXED, __HIP_MEMORY_SCOPE_AGENT);
      int q = u >> 2;
      hyf[(q ^ ((q >> 3) & 7)) * 4 + (u & 3)] = v;
    }
    __syncthreads();

    // ---- phase E: RFF wx = hy(t+1) @ W_rff^T for rows m*32+rloc ----
    float acc = 0.f;
    #pragma unroll
    for (int i = 0; i < 8; ++i) {
      int q = kseg * 8 + i;
      float4 h4 = ((const float4*)hyf)[q ^ ((q >> 3) & 7)];
      acc = fmaf(h4.x, wr[4 * i], acc);
      acc = fmaf(h4.y, wr[4 * i + 1], acc);
      acc = fmaf(h4.z, wr[4 * i + 2], acc);
      acc = fmaf(h4.w, wr[4 * i + 3], acc);
    }
    acc += __shfl_xor(acc, 1); acc += __shfl_xor(acc, 2);
    acc += __shfl_xor(acc, 4); acc += __shfl_xor(acc, 8);
    zc += cosf(acc); zs += sinf(acc);
  }

  if (u < 64) out[(size_t)Bz * Hz + (size_t)b * Hz + c0 + u] = hy;
  if (kseg == 0) {
    const float sc = 0.0625f / 2048.f;   // (1/sqrt(256)) / L
    out[(size_t)b * Hz + m * 32 + rloc] = zc * sc;
    out[(size_t)b * Hz + HALFz + m * 32 + rloc] = zs * sc;
  }
}

// ---------------- fallback: single-block-per-batch (R1 kernel, no ws) ----------------
__global__ __launch_bounds__(512) void coesn_scan_fb(
    const float* __restrict__ x, const float* __restrict__ x2h,
    const float* __restrict__ h2h, const float* __restrict__ bias,
    const float* __restrict__ gam, const float* __restrict__ eps,
    const float* __restrict__ W_rff, float* __restrict__ out) {
  const int b = blockIdx.x;
  const int u = threadIdx.x;
  __shared__ __align__(16) float hy_lds[Hz];
  __shared__ __align__(16) float x_lds[Iz];
  __shared__ float4 part[4][128];
  __shared__ float wx_lds[HALFz];

  float hy = 0.f, hz = 0.f, zsum = 0.f;
  const float bu = bias[u];
  const float gu = gam[u];
  const float eu = eps[u];

  const int kq = u >> 7;
  const int g  = u & 127;
  const int jj = u >> 2;
  const int ks = u & 3;

  const float4* __restrict__ H4 = (const float4*)h2h;
  const float4* __restrict__ X2 = (const float4*)x2h;
  const float4* __restrict__ W4 = (const float4*)W_rff;
  const float4* __restrict__ XG = (const float4*)x;
  const float4* hy4 = (const float4*)hy_lds;

  hy_lds[u] = 0.f;
  if (u < 16) ((float4*)x_lds)[u] = XG[(long)b * Lz * 16 + u];
  __syncthreads();

  for (int t = 0; t < Lz; ++t) {
    float4 p = make_float4(0.f, 0.f, 0.f, 0.f);
    {
      const float4* hp = (const float4*)&hy_lds[kq << 7];
      #pragma unroll 8
      for (int k4 = 0; k4 < 32; ++k4) {
        float4 hv = hp[k4];
        const float4* wr2 = &H4[(size_t)((kq << 7) + (k4 << 2)) * 128 + g];
        float4 w0 = wr2[0]; float4 w1 = wr2[128]; float4 w2 = wr2[256]; float4 w3 = wr2[384];
        FMA4(p, hv.x, w0); FMA4(p, hv.y, w1); FMA4(p, hv.z, w2); FMA4(p, hv.w, w3);
      }
      const float4* xp = (const float4*)&x_lds[kq << 4];
      #pragma unroll
      for (int k4 = 0; k4 < 4; ++k4) {
        float4 xv = xp[k4];
        const float4* wr2 = &X2[(size_t)((kq << 4) + (k4 << 2)) * 128 + g];
        float4 w0 = wr2[0]; float4 w1 = wr2[128]; float4 w2 = wr2[256]; float4 w3 = wr2[384];
        FMA4(p, xv.x, w0); FMA4(p, xv.y, w1); FMA4(p, xv.z, w2); FMA4(p, xv.w, w3);
      }
    }
    part[kq][g] = p;
    __syncthreads();
    {
      const float* pp = (const float*)part;
      float s = (pp[u] + pp[512 + u]) + (pp[1024 + u] + pp[1536 + u]);
      float pre = tanhf(s + bu);
      float hzn = fmaf(DTz, pre - gu * hy - eu * hz, hz);
      hy = fmaf(DTz, hzn, hy);
      hz = hzn;
      hy_lds[u] = hy;
      if (u < 16 && t + 1 < Lz)
        ((float4*)x_lds)[u] = XG[((long)b * Lz + (t + 1)) * 16 + u];
    }
    __syncthreads();
    {
      float4 acc0 = make_float4(0.f,0.f,0.f,0.f), acc1 = make_float4(0.f,0.f,0.f,0.f);
      #pragma unroll 4
      for (int it = 0; it < 32; ++it) {
        int k4 = (it << 2) + ks;
        float4 hv = hy4[k4];
        float4 w0 = W4[(size_t)jj * 128 + k4];
        float4 w1 = W4[(size_t)(jj + 128) * 128 + k4];
        acc0.x = fmaf(hv.x, w0.x, acc0.x); acc0.y = fmaf(hv.y, w0.y, acc0.y);
        acc0.z = fmaf(hv.z, w0.z, acc0.z); acc0.w = fmaf(hv.w, w0.w, acc0.w);
        acc1.x = fmaf(hv.x, w1.x, acc1.x); acc1.y = fmaf(hv.y, w1.y, acc1.y);
        acc1.z = fmaf(hv.z, w1.z, acc1.z); acc1.w = fmaf(hv.w, w1.w, acc1.w);
      }
      float a0 = (acc0.x + acc0.y) + (acc0.z + acc0.w);
      float a1 = (acc1.x + acc1.y) + (acc1.z + acc1.w);
      a0 += __shfl_xor(a0, 1); a0 += __shfl_xor(a0, 2);
      a1 += __shfl_xor(a1, 1); a1 += __shfl_xor(a1, 2);
      if (ks == 0) { wx_lds[jj] = a0; wx_lds[jj + 128] = a1; }
    }
    __syncthreads();
    {
      float v = wx_lds[u & 255];
      zsum += (u < HALFz) ? cosf(v) : sinf(v);
    }
  }
  out[(long)b * Hz + u] = zsum * (0.0625f / 2048.f);
  out[(long)Bz * Hz + (long)b * Hz + u] = hy;
}

extern "C" void kernel_launch(void* const* d_in, const int* in_sizes, int n_in,
                              void* d_out, int out_size, void* d_ws, size_t ws_size,
                              hipStream_t stream) {
  const float* x    = (const float*)d_in[0];
  const float* x2h  = (const float*)d_in[1];
  const float* h2h  = (const float*)d_in[2];
  const float* bias = (const float*)d_in[3];
  const float* gam  = (const float*)d_in[4];
  const float* eps  = (const float*)d_in[5];
  const float* wrff = (const float*)d_in[6];
  float* out = (float*)d_out;

  // ws layout: [0,4096) counters (32 groups x 128B), [4096, 4096+131072) hy exchange
  const size_t WS_NEED = 4096 + (size_t)2 * Bz * Hz * sizeof(float);
  const size_t LDS_BYTES = (size_t)(576 * 64 + 512 + 128 + 512) * sizeof(float); // 152064

  bool ok = (ws_size >= WS_NEED);
  if (ok) {
    unsigned* cnt = (unsigned*)d_ws;
    float* gbuf = (float*)((char*)d_ws + 4096);
    (void)hipFuncSetAttribute((const void*)coesn_coop,
                              hipFuncAttributeMaxDynamicSharedMemorySize,
                              (int)LDS_BYTES);
    hipMemsetAsync(d_ws, 0, 4096, stream);
    void* args[] = { (void*)&x, (void*)&x2h, (void*)&h2h, (void*)&bias,
                     (void*)&gam, (void*)&eps, (void*)&wrff,
                     (void*)&gbuf, (void*)&cnt, (void*)&out };
    hipError_t e = hipLaunchCooperativeKernel((const void*)coesn_coop,
                                              dim3(Bz * NMEM), dim3(TPB),
                                              args, (unsigned)LDS_BYTES, stream);
    if (e != hipSuccess) ok = false;
  }
  if (!ok) {
    coesn_scan_fb<<<Bz, 512, 0, stream>>>(x, x2h, h2h, bias, gam, eps, wrff, out);
  }
}

// Round 3
// 3552.732 us; speedup vs baseline: 6.5720x; 2.7841x over previous
//
#include <hip/hip_runtime.h>
#include <math.h>

#define Bz 32
#define Lz 2048
#define Iz 64
#define Hz 512
#define HALFz 256
#define DTz 0.05f
#define NMEM 8
#define TPB 512

#define FMA4(P, S, W) do { (P).x = fmaf((S), (W).x, (P).x); (P).y = fmaf((S), (W).y, (P).y); \
                           (P).z = fmaf((S), (W).z, (P).z); (P).w = fmaf((S), (W).w, (P).w); } while(0)

// ================= tag-sync cooperative kernel (primary) =================
// 8 blocks per batch element. Member m owns H-cols [m*64, m*64+64) with the
// h2h/x2h column slice held ENTIRELY IN REGISTERS (16+2 float4/thread) and
// W_rff rows [m*32,m*32+32) in registers. Per-step cross-member hy exchange:
// each fp32 sent as 2 dwords of {16 payload bits | 16-bit step tag} via
// relaxed agent-scope atomics (double-buffered). Readers self-sync by
// polling their own column's tags — no counters, no fences, 1 MALL trip.
__global__ __launch_bounds__(TPB, 2) void coesn_tag(
    const float* __restrict__ x, const float* __restrict__ x2h,
    const float* __restrict__ h2h, const float* __restrict__ bias,
    const float* __restrict__ gam, const float* __restrict__ eps,
    const float* __restrict__ W_rff, unsigned* __restrict__ gbuf,
    float* __restrict__ out) {
  __shared__ __align__(16) float hyf[Hz];        // swizzled hy(t)
  __shared__ __align__(16) float xb[2][Iz];      // x_t double buffer
  __shared__ __align__(16) float part[8][64];    // [wave][col] partials

  const int b    = blockIdx.x & 31;
  const int m    = blockIdx.x >> 5;
  const int u    = threadIdx.x;
  const int c0   = m * 64;
  const int ksl  = u >> 4;       // 0..31: K-slice (16 h2h rows + 2 x2h rows)
  const int cg   = u & 15;       // float4 column group within the 64-col slice
  const int wv   = u >> 6;       // wave id == owner-member of global column u
  const int lane = u & 63;
  const int rloc = u >> 4;       // RFF local row
  const int kseg = u & 15;       // RFF K segment

  // ---- weight slices into registers (one-time) ----
  float4 wreg[16];
  #pragma unroll
  for (int k = 0; k < 16; ++k)
    wreg[k] = *(const float4*)(h2h + (size_t)(ksl * 16 + k) * Hz + c0 + 4 * cg);
  float4 xreg[2];
  #pragma unroll
  for (int j = 0; j < 2; ++j)
    xreg[j] = *(const float4*)(x2h + (size_t)(ksl * 2 + j) * Hz + c0 + 4 * cg);
  float wr[32];
  {
    const float* wp = W_rff + (size_t)(m * 32 + rloc) * Hz + kseg * 32;
    #pragma unroll
    for (int j = 0; j < 32; ++j) wr[j] = wp[j];
  }

  float hy = 0.f, hz = 0.f, bu = 0.f, gu = 0.f, eu = 0.f;
  if (u < 64) { bu = bias[c0 + u]; gu = gam[c0 + u]; eu = eps[c0 + u]; }
  hyf[u] = 0.f;
  if (u < 16) ((float4*)xb[0])[u] = ((const float4*)(x + (size_t)b * Lz * Iz))[u];
  float zc = 0.f, zs = 0.f;
  __syncthreads();

  for (int t = 0; t < Lz; ++t) {
    // ---- phase A: matvec partials from registers ----
    float hv[16];
    #pragma unroll
    for (int j = 0; j < 4; ++j) {
      int q = ksl * 4 + j;
      float4 h4 = ((const float4*)hyf)[q ^ ((q >> 3) & 7)];
      hv[4 * j] = h4.x; hv[4 * j + 1] = h4.y; hv[4 * j + 2] = h4.z; hv[4 * j + 3] = h4.w;
    }
    float4 p = make_float4(0.f, 0.f, 0.f, 0.f);
    #pragma unroll
    for (int k = 0; k < 16; ++k) FMA4(p, hv[k], wreg[k]);
    {
      const float* xcur = xb[t & 1];
      FMA4(p, xcur[ksl * 2], xreg[0]);
      FMA4(p, xcur[ksl * 2 + 1], xreg[1]);
    }
    if (u < 16 && t + 1 < Lz)
      ((float4*)xb[(t + 1) & 1])[u] =
          ((const float4*)(x + ((size_t)b * Lz + (t + 1)) * Iz))[u];
    // reduce 4 K-slices within the wave (lanes l, l^16, l^32, l^48 share cg)
    p.x += __shfl_xor(p.x, 16); p.y += __shfl_xor(p.y, 16);
    p.z += __shfl_xor(p.z, 16); p.w += __shfl_xor(p.w, 16);
    p.x += __shfl_xor(p.x, 32); p.y += __shfl_xor(p.y, 32);
    p.z += __shfl_xor(p.z, 32); p.w += __shfl_xor(p.w, 32);
    if (lane < 16) ((float4*)part[wv])[lane] = p;
    __syncthreads();   // (1)

    const unsigned tag = (unsigned)(t + 1);
    unsigned* buf = gbuf + ((size_t)((t + 1) & 1) * Bz + b) * (2 * Hz);

    // ---- phase B: owners (wave 0) reduce + state update + publish ----
    if (u < 64) {
      float s = 0.f;
      #pragma unroll
      for (int w = 0; w < 8; ++w) s += part[w][u];
      float pre = tanhf(s + bu);
      float hzn = fmaf(DTz, pre - gu * hy - eu * hz, hz);
      hy = fmaf(DTz, hzn, hy);
      hz = hzn;
      unsigned bits = __float_as_uint(hy);
      __hip_atomic_store(buf + c0 + u, (bits & 0xffff0000u) | tag,
                         __ATOMIC_RELAXED, __HIP_MEMORY_SCOPE_AGENT);
      __hip_atomic_store(buf + Hz + c0 + u, (bits << 16) | tag,
                         __ATOMIC_RELAXED, __HIP_MEMORY_SCOPE_AGENT);
      int q = (c0 + u) >> 2;
      hyf[(q ^ ((q >> 3) & 7)) * 4 + (u & 3)] = hy;   // local cols via LDS
    }
    // ---- phase D: poll remote columns (self-validating tags) ----
    if (wv != m) {
      unsigned h, l; int guard = 0;
      do {
        h = __hip_atomic_load(buf + u, __ATOMIC_RELAXED, __HIP_MEMORY_SCOPE_AGENT);
        l = __hip_atomic_load(buf + Hz + u, __ATOMIC_RELAXED, __HIP_MEMORY_SCOPE_AGENT);
      } while ((((h ^ tag) | (l ^ tag)) & 0xffffu) && ++guard < (1 << 20));
      int q = u >> 2;
      hyf[(q ^ ((q >> 3) & 7)) * 4 + (u & 3)] =
          __uint_as_float((h & 0xffff0000u) | (l >> 16));
    }
    __syncthreads();   // (2)

    // ---- phase E: RFF from registers on hy(t+1) ----
    float acc = 0.f;
    #pragma unroll
    for (int i = 0; i < 8; ++i) {
      int q = kseg * 8 + i;
      float4 h4 = ((const float4*)hyf)[q ^ ((q >> 3) & 7)];
      acc = fmaf(h4.x, wr[4 * i], acc);
      acc = fmaf(h4.y, wr[4 * i + 1], acc);
      acc = fmaf(h4.z, wr[4 * i + 2], acc);
      acc = fmaf(h4.w, wr[4 * i + 3], acc);
    }
    acc += __shfl_xor(acc, 1); acc += __shfl_xor(acc, 2);
    acc += __shfl_xor(acc, 4); acc += __shfl_xor(acc, 8);
    float sv, cv;
    __sincosf(acc, &sv, &cv);
    zc += cv; zs += sv;
  }

  if (u < 64) out[(size_t)Bz * Hz + (size_t)b * Hz + c0 + u] = hy;
  if (kseg == 0) {
    const float sc = 0.0625f / 2048.f;   // (1/sqrt(256)) / L
    out[(size_t)b * Hz + m * 32 + rloc] = zc * sc;
    out[(size_t)b * Hz + HALFz + m * 32 + rloc] = zs * sc;
  }
}

// ================= counter-sync cooperative kernel (secondary, proven R2) =================
__global__ __launch_bounds__(TPB, 1) void coesn_coop(
    const float* __restrict__ x, const float* __restrict__ x2h,
    const float* __restrict__ h2h, const float* __restrict__ bias,
    const float* __restrict__ gam, const float* __restrict__ eps,
    const float* __restrict__ W_rff, float* __restrict__ gbuf,
    unsigned* __restrict__ cnt, float* __restrict__ out) {
  extern __shared__ float smem[];
  float* hs   = smem;
  float* hyf  = smem + 576 * 64;
  float* xb   = hyf + 512;
  float* part = xb + 128;

  const int b  = blockIdx.x & 31;
  const int m  = blockIdx.x >> 5;
  const int u  = threadIdx.x;
  const int c0 = m * 64;

  for (int idx = u; idx < Hz * 64; idx += TPB)
    hs[idx] = h2h[(size_t)(idx >> 6) * Hz + c0 + (idx & 63)];
  for (int idx = u; idx < Iz * 64; idx += TPB)
    hs[(Hz + (idx >> 6)) * 64 + (idx & 63)] = x2h[(size_t)(idx >> 6) * Hz + c0 + (idx & 63)];

  const int rloc = u >> 4;
  const int kseg = u & 15;
  float wr[32];
  {
    const float* wp = W_rff + (size_t)(m * 32 + rloc) * Hz + kseg * 32;
    #pragma unroll
    for (int j = 0; j < 32; ++j) wr[j] = wp[j];
  }

  float hy = 0.f, hz = 0.f, bu = 0.f, gu = 0.f, eu = 0.f;
  if (u < 64) { bu = bias[c0 + u]; gu = gam[c0 + u]; eu = eps[c0 + u]; }
  hyf[u] = 0.f;
  if (u < 16) ((float4*)xb)[u] = ((const float4*)(x + (size_t)b * Lz * Iz))[u];

  float zc = 0.f, zs = 0.f;
  unsigned* cb = cnt + b * 32;
  __syncthreads();

  const int cg  = u & 15;
  const int ksl = u >> 4;

  for (int t = 0; t < Lz; ++t) {
    float hv[16];
    #pragma unroll
    for (int j = 0; j < 4; ++j) {
      int q = ksl * 4 + j;
      float4 h4 = ((const float4*)hyf)[q ^ ((q >> 3) & 7)];
      hv[4 * j] = h4.x; hv[4 * j + 1] = h4.y; hv[4 * j + 2] = h4.z; hv[4 * j + 3] = h4.w;
    }
    float4 p = make_float4(0.f, 0.f, 0.f, 0.f);
    #pragma unroll
    for (int k = 0; k < 16; ++k) {
      float4 w4 = ((const float4*)(hs + (ksl * 16 + k) * 64))[cg];
      FMA4(p, hv[k], w4);
    }
    const float* xcur = xb + (t & 1) * 64;
    #pragma unroll
    for (int j = 0; j < 2; ++j) {
      float xv = xcur[ksl * 2 + j];
      float4 w4 = ((const float4*)(hs + (Hz + ksl * 2 + j) * 64))[cg];
      FMA4(p, xv, w4);
    }
    if (u < 16 && t + 1 < Lz)
      ((float4*)(xb + ((t + 1) & 1) * 64))[u] =
          ((const float4*)(x + ((size_t)b * Lz + (t + 1)) * Iz))[u];
    p.x += __shfl_xor(p.x, 16); p.y += __shfl_xor(p.y, 16);
    p.z += __shfl_xor(p.z, 16); p.w += __shfl_xor(p.w, 16);
    p.x += __shfl_xor(p.x, 32); p.y += __shfl_xor(p.y, 32);
    p.z += __shfl_xor(p.z, 32); p.w += __shfl_xor(p.w, 32);
    const int lane = u & 63, wvv = u >> 6;
    if (lane < 16) ((float4*)part)[wvv * 16 + lane] = p;
    __syncthreads();

    if (u < 64) {
      float s = 0.f;
      #pragma unroll
      for (int j = 0; j < 8; ++j) s += part[j * 64 + u];
      float pre = tanhf(s + bu);
      float hzn = fmaf(DTz, pre - gu * hy - eu * hz, hz);
      hy = fmaf(DTz, hzn, hy);
      hz = hzn;
      __hip_atomic_store(gbuf + ((t + 1) & 1) * (Bz * Hz) + b * Hz + c0 + u, hy,
                         __ATOMIC_RELAXED, __HIP_MEMORY_SCOPE_AGENT);
    }
    if (u == 0) {
      __hip_atomic_fetch_add(cb, 1u, __ATOMIC_RELEASE, __HIP_MEMORY_SCOPE_AGENT);
      const unsigned target = (unsigned)(NMEM * (t + 1));
      unsigned v; long guard = 0;
      do { v = __hip_atomic_load(cb, __ATOMIC_RELAXED, __HIP_MEMORY_SCOPE_AGENT); }
      while (v < target && ++guard < (1L << 22));
      (void)__hip_atomic_load(cb, __ATOMIC_ACQUIRE, __HIP_MEMORY_SCOPE_AGENT);
    }
    __syncthreads();

    {
      float v = __hip_atomic_load(gbuf + ((t + 1) & 1) * (Bz * Hz) + b * Hz + u,
                                  __ATOMIC_RELAXED, __HIP_MEMORY_SCOPE_AGENT);
      int q = u >> 2;
      hyf[(q ^ ((q >> 3) & 7)) * 4 + (u & 3)] = v;
    }
    __syncthreads();

    float acc = 0.f;
    #pragma unroll
    for (int i = 0; i < 8; ++i) {
      int q = kseg * 8 + i;
      float4 h4 = ((const float4*)hyf)[q ^ ((q >> 3) & 7)];
      acc = fmaf(h4.x, wr[4 * i], acc);
      acc = fmaf(h4.y, wr[4 * i + 1], acc);
      acc = fmaf(h4.z, wr[4 * i + 2], acc);
      acc = fmaf(h4.w, wr[4 * i + 3], acc);
    }
    acc += __shfl_xor(acc, 1); acc += __shfl_xor(acc, 2);
    acc += __shfl_xor(acc, 4); acc += __shfl_xor(acc, 8);
    zc += cosf(acc); zs += sinf(acc);
  }

  if (u < 64) out[(size_t)Bz * Hz + (size_t)b * Hz + c0 + u] = hy;
  if (kseg == 0) {
    const float sc = 0.0625f / 2048.f;
    out[(size_t)b * Hz + m * 32 + rloc] = zc * sc;
    out[(size_t)b * Hz + HALFz + m * 32 + rloc] = zs * sc;
  }
}

// ================= single-block-per-batch fallback (tertiary, proven R1) =================
__global__ __launch_bounds__(512) void coesn_scan_fb(
    const float* __restrict__ x, const float* __restrict__ x2h,
    const float* __restrict__ h2h, const float* __restrict__ bias,
    const float* __restrict__ gam, const float* __restrict__ eps,
    const float* __restrict__ W_rff, float* __restrict__ out) {
  const int b = blockIdx.x;
  const int u = threadIdx.x;
  __shared__ __align__(16) float hy_lds[Hz];
  __shared__ __align__(16) float x_lds[Iz];
  __shared__ float4 part[4][128];
  __shared__ float wx_lds[HALFz];

  float hy = 0.f, hz = 0.f, zsum = 0.f;
  const float bu = bias[u];
  const float gu = gam[u];
  const float eu = eps[u];

  const int kq = u >> 7;
  const int g  = u & 127;
  const int jj = u >> 2;
  const int ks = u & 3;

  const float4* __restrict__ H4 = (const float4*)h2h;
  const float4* __restrict__ X2 = (const float4*)x2h;
  const float4* __restrict__ W4 = (const float4*)W_rff;
  const float4* __restrict__ XG = (const float4*)x;
  const float4* hy4 = (const float4*)hy_lds;

  hy_lds[u] = 0.f;
  if (u < 16) ((float4*)x_lds)[u] = XG[(long)b * Lz * 16 + u];
  __syncthreads();

  for (int t = 0; t < Lz; ++t) {
    float4 p = make_float4(0.f, 0.f, 0.f, 0.f);
    {
      const float4* hp = (const float4*)&hy_lds[kq << 7];
      #pragma unroll 8
      for (int k4 = 0; k4 < 32; ++k4) {
        float4 hv = hp[k4];
        const float4* wr2 = &H4[(size_t)((kq << 7) + (k4 << 2)) * 128 + g];
        float4 w0 = wr2[0]; float4 w1 = wr2[128]; float4 w2 = wr2[256]; float4 w3 = wr2[384];
        FMA4(p, hv.x, w0); FMA4(p, hv.y, w1); FMA4(p, hv.z, w2); FMA4(p, hv.w, w3);
      }
      const float4* xp = (const float4*)&x_lds[kq << 4];
      #pragma unroll
      for (int k4 = 0; k4 < 4; ++k4) {
        float4 xv = xp[k4];
        const float4* wr2 = &X2[(size_t)((kq << 4) + (k4 << 2)) * 128 + g];
        float4 w0 = wr2[0]; float4 w1 = wr2[128]; float4 w2 = wr2[256]; float4 w3 = wr2[384];
        FMA4(p, xv.x, w0); FMA4(p, xv.y, w1); FMA4(p, xv.z, w2); FMA4(p, xv.w, w3);
      }
    }
    part[kq][g] = p;
    __syncthreads();
    {
      const float* pp = (const float*)part;
      float s = (pp[u] + pp[512 + u]) + (pp[1024 + u] + pp[1536 + u]);
      float pre = tanhf(s + bu);
      float hzn = fmaf(DTz, pre - gu * hy - eu * hz, hz);
      hy = fmaf(DTz, hzn, hy);
      hz = hzn;
      hy_lds[u] = hy;
      if (u < 16 && t + 1 < Lz)
        ((float4*)x_lds)[u] = XG[((long)b * Lz + (t + 1)) * 16 + u];
    }
    __syncthreads();
    {
      float4 acc0 = make_float4(0.f,0.f,0.f,0.f), acc1 = make_float4(0.f,0.f,0.f,0.f);
      #pragma unroll 4
      for (int it = 0; it < 32; ++it) {
        int k4 = (it << 2) + ks;
        float4 hv = hy4[k4];
        float4 w0 = W4[(size_t)jj * 128 + k4];
        float4 w1 = W4[(size_t)(jj + 128) * 128 + k4];
        acc0.x = fmaf(hv.x, w0.x, acc0.x); acc0.y = fmaf(hv.y, w0.y, acc0.y);
        acc0.z = fmaf(hv.z, w0.z, acc0.z); acc0.w = fmaf(hv.w, w0.w, acc0.w);
        acc1.x = fmaf(hv.x, w1.x, acc1.x); acc1.y = fmaf(hv.y, w1.y, acc1.y);
        acc1.z = fmaf(hv.z, w1.z, acc1.z); acc1.w = fmaf(hv.w, w1.w, acc1.w);
      }
      float a0 = (acc0.x + acc0.y) + (acc0.z + acc0.w);
      float a1 = (acc1.x + acc1.y) + (acc1.z + acc1.w);
      a0 += __shfl_xor(a0, 1); a0 += __shfl_xor(a0, 2);
      a1 += __shfl_xor(a1, 1); a1 += __shfl_xor(a1, 2);
      if (ks == 0) { wx_lds[jj] = a0; wx_lds[jj + 128] = a1; }
    }
    __syncthreads();
    {
      float v = wx_lds[u & 255];
      zsum += (u < HALFz) ? cosf(v) : sinf(v);
    }
  }
  out[(long)b * Hz + u] = zsum * (0.0625f / 2048.f);
  out[(long)Bz * Hz + (long)b * Hz + u] = hy;
}

extern "C" void kernel_launch(void* const* d_in, const int* in_sizes, int n_in,
                              void* d_out, int out_size, void* d_ws, size_t ws_size,
                              hipStream_t stream) {
  const float* x    = (const float*)d_in[0];
  const float* x2h  = (const float*)d_in[1];
  const float* h2h  = (const float*)d_in[2];
  const float* bias = (const float*)d_in[3];
  const float* gam  = (const float*)d_in[4];
  const float* eps  = (const float*)d_in[5];
  const float* wrff = (const float*)d_in[6];
  float* out = (float*)d_out;

  // --- primary: tag-sync kernel; ws = 2 buf x 32 groups x 2 halves x 512 dwords = 256KB
  const size_t WS_TAG = (size_t)2 * Bz * 2 * Hz * sizeof(unsigned);
  if (ws_size >= WS_TAG) {
    unsigned* gbuf = (unsigned*)d_ws;
    hipMemsetAsync(d_ws, 0, WS_TAG, stream);
    void* args[] = { (void*)&x, (void*)&x2h, (void*)&h2h, (void*)&bias,
                     (void*)&gam, (void*)&eps, (void*)&wrff,
                     (void*)&gbuf, (void*)&out };
    hipError_t e = hipLaunchCooperativeKernel((const void*)coesn_tag,
                                              dim3(Bz * NMEM), dim3(TPB),
                                              args, 0, stream);
    if (e == hipSuccess) return;
  }

  // --- secondary: counter-sync kernel (R2, proven)
  const size_t WS_CNT = 4096 + (size_t)2 * Bz * Hz * sizeof(float);
  const size_t LDS_BYTES = (size_t)(576 * 64 + 512 + 128 + 512) * sizeof(float);
  if (ws_size >= WS_CNT) {
    unsigned* cnt = (unsigned*)d_ws;
    float* gbuf = (float*)((char*)d_ws + 4096);
    (void)hipFuncSetAttribute((const void*)coesn_coop,
                              hipFuncAttributeMaxDynamicSharedMemorySize,
                              (int)LDS_BYTES);
    hipMemsetAsync(d_ws, 0, 4096, stream);
    void* args[] = { (void*)&x, (void*)&x2h, (void*)&h2h, (void*)&bias,
                     (void*)&gam, (void*)&eps, (void*)&wrff,
                     (void*)&gbuf, (void*)&cnt, (void*)&out };
    hipError_t e = hipLaunchCooperativeKernel((const void*)coesn_coop,
                                              dim3(Bz * NMEM), dim3(TPB),
                                              args, (unsigned)LDS_BYTES, stream);
    if (e == hipSuccess) return;
  }

  // --- tertiary: single-block-per-batch
  coesn_scan_fb<<<Bz, 512, 0, stream>>>(x, x2h, h2h, bias, gam, eps, wrff, out);
}